// Round 1
// baseline (321.416 us; speedup 1.0000x reference)
//
#include <hip/hip_runtime.h>

typedef __attribute__((ext_vector_type(4))) float v4f;
typedef __attribute__((ext_vector_type(8))) short v8s;
typedef __attribute__((ext_vector_type(4))) short v4s;

__device__ __forceinline__ short f2bf(float f) {
  union { float f; unsigned u; } v; v.f = f;
  unsigned r = v.u + 0x7FFFu + ((v.u >> 16) & 1u);  // RNE
  return (short)(r >> 16);
}

// Detect whether the index array is int64 (odd 32-bit words all zero) or int32.
__global__ void detect_i64(const unsigned* __restrict__ e, int* __restrict__ flag) {
  if (threadIdx.x == 0) {
    unsigned o = 0;
    for (int i = 0; i < 32; ++i) o |= e[2 * i + 1];
    *flag = (o == 0) ? 1 : 0;
  }
}

// Pack W1 [128x256] and W2 [256x256] (row-major [k][n], fp32) into bf16
// MFMA A-operand fragment order for the TRANSPOSED product (W^T as A):
//   lane l of fragment (mt, kt) holds A'[n = mt*16 + (l&15)][k = kt*32 + (l>>4)*8 + j]
//   = W[k][n], j = 0..7 contiguous.
// pW1: frag = mt*4 + kt  (mt 0..15, kt 0..3)   -> 64 frags * 512 shorts
// pW2: frag = mt*8 + kt  (mt 0..15, kt 0..7)   -> 128 frags * 512 shorts
__global__ void pack_weights(const float* __restrict__ W1, const float* __restrict__ W2,
                             short* __restrict__ pW1, short* __restrict__ pW2) {
  int tid = blockIdx.x * 256 + threadIdx.x;
  if (tid < 32768) {
    int j = tid & 7, l = (tid >> 3) & 63, frag = tid >> 9;
    int mt = frag >> 2, kt = frag & 3;
    int n = mt * 16 + (l & 15);
    int k = kt * 32 + ((l >> 4) * 8) + j;
    pW1[tid] = f2bf(W1[k * 256 + n]);
  } else if (tid < 98304) {
    int t2 = tid - 32768;
    int j = t2 & 7, l = (t2 >> 3) & 63, frag = t2 >> 9;
    int mt = frag >> 3, kt = frag & 7;
    int n = mt * 16 + (l & 15);
    int k = kt * 32 + ((l >> 4) * 8) + j;
    pW2[t2] = f2bf(W2[k * 256 + n]);
  }
}

#define LDX_S 136   // 128 + 8 pad (keeps 16B alignment, spreads banks)
#define LDH_S 264   // 256 + 8 pad

// Fused 3-layer MLP over a 64-edge tile. 256 threads = 4 waves.
// Wave w computes hidden rows [w*64, w*64+64) x all 64 edges (transposed GEMM:
// D[n_hidden][edge] = sum_k W[k][n] * X[edge][k]).
__global__ __launch_bounds__(256, 2) void mlp_fused(
    const float* __restrict__ xu, const float* __restrict__ xm,
    const void* __restrict__ eidx_raw, const int* __restrict__ flag,
    const short* __restrict__ pW1, const short* __restrict__ pW2,
    const float* __restrict__ b1, const float* __restrict__ b2,
    const float* __restrict__ W3, const float* __restrict__ b3,
    float* __restrict__ out, int E)
{
  __shared__ __align__(16) short ldsX[64 * LDX_S];   // [edge][k0..127] bf16
  __shared__ __align__(16) short ldsH[64 * LDH_S];   // [edge][h0..255] bf16
  __shared__ __align__(16) float ldsB1[256];
  __shared__ __align__(16) float ldsB2[256];
  __shared__ __align__(16) float ldsW3[256];
  __shared__ __align__(16) float ldsPart[64 * 16];   // [edge][wave*4+quad]

  const int t = threadIdx.x;

  // stage biases / W3
  ldsB1[t] = b1[t]; ldsB2[t] = b2[t]; ldsW3[t] = W3[t];

  // ---- gather: 4 threads per edge, 16 floats (user) + 16 floats (movie) each
  {
    const int i = t >> 2, q = t & 3;
    int gE = blockIdx.x * 64 + i;
    if (gE >= E) gE = 0;
    int row, col;
    if (*flag) {
      const long long* p = (const long long*)eidx_raw;
      row = (int)p[gE]; col = (int)p[(long long)E + gE];
    } else {
      const int* p = (const int*)eidx_raw;
      row = p[gE]; col = p[E + gE];
    }
    const v4f* pu = (const v4f*)(xu + (long long)row * 64 + q * 16);
    const v4f* pm = (const v4f*)(xm + (long long)col * 64 + q * 16);
    v4f U[4], M[4];
#pragma unroll
    for (int s = 0; s < 4; ++s) { U[s] = pu[s]; M[s] = pm[s]; }
    v8s u0, u1, m0, m1;
#pragma unroll
    for (int c = 0; c < 4; ++c) {
      u0[c] = f2bf(U[0][c]); u0[c + 4] = f2bf(U[1][c]);
      u1[c] = f2bf(U[2][c]); u1[c + 4] = f2bf(U[3][c]);
      m0[c] = f2bf(M[0][c]); m0[c + 4] = f2bf(M[1][c]);
      m1[c] = f2bf(M[2][c]); m1[c + 4] = f2bf(M[3][c]);
    }
    short* px = &ldsX[i * LDX_S + q * 16];
    *(v8s*)(px)      = u0; *(v8s*)(px + 8)  = u1;   // user -> k 0..63
    *(v8s*)(px + 64) = m0; *(v8s*)(px + 72) = m1;   // movie -> k 64..127
  }
  __syncthreads();

  const int w    = t >> 6;        // wave 0..3 : hidden slice w*64
  const int lane = t & 63;
  const int quad = lane >> 4;
  const int lp   = lane & 15;

  // ---- layer 1: D1[n][e] over K=128 (4 k-steps)
  v4f acc[4][4] = {};
  const v8s* w1v = (const v8s*)pW1;
#pragma unroll
  for (int kt = 0; kt < 4; ++kt) {
    v8s a[4], b[4];
#pragma unroll
    for (int mi = 0; mi < 4; ++mi)
      a[mi] = w1v[(((w * 4 + mi) * 4) + kt) * 64 + lane];
#pragma unroll
    for (int ni = 0; ni < 4; ++ni)
      b[ni] = *(const v8s*)&ldsX[(ni * 16 + lp) * LDX_S + kt * 32 + quad * 8];
#pragma unroll
    for (int mi = 0; mi < 4; ++mi)
#pragma unroll
      for (int ni = 0; ni < 4; ++ni)
        acc[mi][ni] = __builtin_amdgcn_mfma_f32_16x16x32_bf16(a[mi], b[ni], acc[mi][ni], 0, 0, 0);
  }

  // ---- epilogue 1: bias + relu + bf16 -> ldsH[e][n]
#pragma unroll
  for (int mi = 0; mi < 4; ++mi) {
    int nh0 = w * 64 + mi * 16 + quad * 4;          // 4 consecutive hidden dims
    v4f bias = *(const v4f*)&ldsB1[nh0];
#pragma unroll
    for (int ni = 0; ni < 4; ++ni) {
      int e = ni * 16 + lp;
      v4f v = acc[mi][ni] + bias;
      v4s s;
#pragma unroll
      for (int r = 0; r < 4; ++r) {
        float x = v[r] > 0.f ? v[r] : 0.f;
        s[r] = f2bf(x);
      }
      *(v4s*)&ldsH[e * LDH_S + nh0] = s;            // ds_write_b64
    }
  }
  __syncthreads();

  // ---- layer 2: D2[n][e] over K=256 (8 k-steps)
  v4f acc2[4][4] = {};
  const v8s* w2v = (const v8s*)pW2;
#pragma unroll
  for (int kt = 0; kt < 8; ++kt) {
    v8s a[4], b[4];
#pragma unroll
    for (int mi = 0; mi < 4; ++mi)
      a[mi] = w2v[(((w * 4 + mi) * 8) + kt) * 64 + lane];
#pragma unroll
    for (int ni = 0; ni < 4; ++ni)
      b[ni] = *(const v8s*)&ldsH[(ni * 16 + lp) * LDH_S + kt * 32 + quad * 8];
#pragma unroll
    for (int mi = 0; mi < 4; ++mi)
#pragma unroll
      for (int ni = 0; ni < 4; ++ni)
        acc2[mi][ni] = __builtin_amdgcn_mfma_f32_16x16x32_bf16(a[mi], b[ni], acc2[mi][ni], 0, 0, 0);
  }

  // ---- layer 3 (fp32): s[e] += relu(h2 + b2) . W3, per-lane partials
  float s[4] = {0.f, 0.f, 0.f, 0.f};
#pragma unroll
  for (int mi = 0; mi < 4; ++mi) {
    int nh0 = w * 64 + mi * 16 + quad * 4;
    v4f bb = *(const v4f*)&ldsB2[nh0];
    v4f ww = *(const v4f*)&ldsW3[nh0];
#pragma unroll
    for (int ni = 0; ni < 4; ++ni) {
      v4f v = acc2[mi][ni] + bb;
#pragma unroll
      for (int r = 0; r < 4; ++r) {
        float x = v[r] > 0.f ? v[r] : 0.f;
        s[ni] += x * ww[r];
      }
    }
  }
#pragma unroll
  for (int ni = 0; ni < 4; ++ni) {
    int e = ni * 16 + lp;
    ldsPart[e * 16 + w * 4 + quad] = s[ni];
  }
  __syncthreads();

  // ---- final reduce: 16 partials per edge
  if (t < 64) {
    const v4f* pp = (const v4f*)&ldsPart[t * 16];
    v4f p0 = pp[0], p1 = pp[1], p2 = pp[2], p3 = pp[3];
    float r = b3[0]
            + (p0[0] + p0[1] + p0[2] + p0[3]) + (p1[0] + p1[1] + p1[2] + p1[3])
            + (p2[0] + p2[1] + p2[2] + p2[3]) + (p3[0] + p3[1] + p3[2] + p3[3]);
    int o = blockIdx.x * 64 + t;
    if (o < E) out[o] = r;
  }
}

extern "C" void kernel_launch(void* const* d_in, const int* in_sizes, int n_in,
                              void* d_out, int out_size, void* d_ws, size_t ws_size,
                              hipStream_t stream) {
  const float* xu  = (const float*)d_in[0];
  const float* xm  = (const float*)d_in[1];
  const void*  ei  = d_in[2];
  const float* W1  = (const float*)d_in[3];
  const float* b1  = (const float*)d_in[4];
  const float* W2  = (const float*)d_in[5];
  const float* b2  = (const float*)d_in[6];
  const float* W3  = (const float*)d_in[7];
  const float* b3  = (const float*)d_in[8];
  float* out = (float*)d_out;

  const int E = in_sizes[2] / 2;

  short* pW1 = (short*)d_ws;          // 32768 shorts = 64 KB
  short* pW2 = pW1 + 32768;           // 65536 shorts = 128 KB
  int*   flag = (int*)(pW2 + 65536);

  hipLaunchKernelGGL(detect_i64, dim3(1), dim3(64), 0, stream, (const unsigned*)ei, flag);
  hipLaunchKernelGGL(pack_weights, dim3(384), dim3(256), 0, stream, W1, W2, pW1, pW2);

  const int nblocks = (E + 63) / 64;
  hipLaunchKernelGGL(mlp_fused, dim3(nblocks), dim3(256), 0, stream,
                     xu, xm, ei, flag, pW1, pW2, b1, b2, W3, b3, out, E);
}